// Round 13
// baseline (122.076 us; speedup 1.0000x reference)
//
#include <hip/hip_runtime.h>

#define BATCH 16
#define HH 512
#define WW 512
#define PLANE (HH*WW)

// Compiler memory-order fences for wave-synchronous LDS exchange.
#define LDS_WAIT()   asm volatile("s_waitcnt lgkmcnt(0)" ::: "memory")
#define WAVE_FENCE() asm volatile("" ::: "memory")

// bf16 pair helpers: word = x in low 16 bits, y in high 16 bits
__device__ __forceinline__ float bf_lo(unsigned u) {
    union { unsigned u; float f; } c; c.u = u << 16; return c.f;
}
__device__ __forceinline__ float bf_hi(unsigned u) {
    union { unsigned u; float f; } c; c.u = u & 0xFFFF0000u; return c.f;
}
__device__ __forceinline__ unsigned f2bf(float f) {   // RTNE, returns low-16 bf16
    union { float f; unsigned u; } c; c.f = f;
    return (c.u + 0x7FFFu + ((c.u >> 16) & 1u)) >> 16;
}
__device__ __forceinline__ unsigned packbf(float x, float y) {
    return f2bf(x) | (f2bf(y) << 16);
}
__device__ __forceinline__ float min3f(float a, float b, float c) {
    return fminf(fminf(a, b), c);    // clang fuses to v_min3_f32
}

// ---------------- K1: guide (channel mean) + 15x15 replicate min-pool -> packed bf16 (g,p) ----------------
#define T1 64
#define HALO 7
#define LW (T1 + 2*HALO)   // 78

__global__ __launch_bounds__(256) void k1_guide_minpool(
    const float* __restrict__ smoky, unsigned* __restrict__ gp)
{
    __shared__ float dcp[LW*LW];          // per-pixel channel min, with replicate halo
    __shared__ float vmn[T1*LW];          // vertical 15-min
    __shared__ unsigned short gsh[T1*T1]; // guide (bf16) for interior
    int nwg = gridDim.x;             // 1024, divisible by 8
    int wg = (blockIdx.x & 7) * (nwg >> 3) + (blockIdx.x >> 3);  // XCD-chunked swizzle
    int img  = wg >> 6;              // 64 tiles per image
    int tile = wg & 63;
    int y0 = (tile >> 3) * T1;
    int x0 = (tile & 7) * T1;
    int t = threadIdx.x;
    const float* s0 = smoky + (size_t)img * 3 * PLANE;
    unsigned* gpl = gp + (size_t)img * PLANE;

    for (int i = t; i < LW*LW; i += 256) {
        int ly = i / LW, lx = i - ly * LW;
        int iy = y0 - HALO + ly, ix = x0 - HALO + lx;
        int cy = min(max(iy, 0), HH-1);
        int cx = min(max(ix, 0), WW-1);
        const float* bp = s0 + cy * WW + cx;
        float c0 = bp[0], c1 = bp[PLANE], c2 = bp[2*PLANE];
        dcp[i] = min3f(c0, c1, c2);
        if (ly >= HALO && ly < HALO+T1 && lx >= HALO && lx < HALO+T1)
            gsh[(ly-HALO)*T1 + (lx-HALO)] = (unsigned short)f2bf((c0 + c1 + c2) * (1.0f/3.0f));
    }
    __syncthreads();
    for (int i = t; i < T1*LW; i += 256) {
        int r = i / LW, c = i - r * LW;
        const float* q = &dcp[r*LW + c];
        float m = min3f(min3f(min3f(q[0*LW],q[1*LW],q[2*LW]),
                              min3f(q[3*LW],q[4*LW],q[5*LW]),
                              min3f(q[6*LW],q[7*LW],q[8*LW])),
                        min3f(q[9*LW],q[10*LW],q[11*LW]),
                        min3f(q[12*LW],q[13*LW],q[14*LW]));
        vmn[i] = m;
    }
    __syncthreads();
    for (int i = t; i < T1*T1; i += 256) {
        int r = i >> 6, c = i & 63;
        const float* q = &vmn[r*LW + c];
        float m = min3f(min3f(min3f(q[0],q[1],q[2]),
                              min3f(q[3],q[4],q[5]),
                              min3f(q[6],q[7],q[8])),
                        min3f(q[9],q[10],q[11]),
                        min3f(q[12],q[13],q[14]));
        gpl[(y0+r)*WW + x0 + c] = (unsigned)gsh[r*T1+c] | (f2bf(m) << 16);
    }
}

// ================= K23: fused cascade (gp -> a,b in LDS ring -> output), wave-autonomous =================
// 4 independent waves per block (16 waves/CU). Wave owns 64 output cols x 16 rows.
// Per iteration t: slide gp col-sums -> exchange1 -> a,b row t (bf16, LDS ring, never HBM)
// -> slide ab col-sums -> exchange2 -> emit row t-7.
#define RSF 16

__global__ __launch_bounds__(256) void k23(
    const unsigned* __restrict__ gp,
    const float* __restrict__ smoky, const float* __restrict__ rho,
    float* __restrict__ out)
{
    __shared__ float    ex1[4][384];      // [wave][quantity*96+slot]  (I,II,P,Ip col-sums; 92 slots used)
    __shared__ unsigned ring[4][16][80];  // [wave][row&15][ab col slot] packed bf16 (a,b)
    __shared__ float2   ex2[4][80];       // [wave][ab col-sum slot] (sumA, sumB)

    int nwg = gridDim.x;             // 1024
    int wg = (blockIdx.x & 7) * (nwg >> 3) + (blockIdx.x >> 3);   // XCD-chunked swizzle
    int w = threadIdx.x >> 6, l = threadIdx.x & 63;
    int gw = wg * 4 + w;             // 0..4095
    int img   = gw >> 8;             // 256 waves per image
    int cg    = (gw >> 5) & 7;       // 8 column groups of 64
    int strip = gw & 31;             // 32 row strips of 16
    int y0 = strip * RSF;
    int c0 = cg * 64;

    const unsigned* gpP = gp + (size_t)img * PLANE;
    const float* sP = smoky + (size_t)img * 3 * PLANE;
    const float* rP = rho   + (size_t)img * 3 * PLANE;
    float* oP = out + (size_t)img * 3 * PLANE;

    // gp col-sum slot s <-> col c0-14+s, s=0..91. Lane l: main slot l, halo slot 64+l (l<28).
    int colA = c0 - 14 + l;          // max 497, min -14
    int colB = c0 + 50 + l;          // halo cols (lanes 0..27): c0+50..c0+77, may be >=512
    bool vA = (colA >= 0);
    bool vB = (l < 28) && (colB < WW);

    // Branchless gp row load (clamped row + select; VMEM count path-independent).
    auto loadgp = [&](int y, unsigned& u0, unsigned& u1) {
        int yc = min(max(y, 0), HH-1);
        const unsigned* r = gpP + (size_t)yc * WW;
        unsigned a = 0u, b = 0u;
        if (vA) a = r[colA];
        if (vB) b = r[colB];
        bool rv = ((unsigned)y < (unsigned)HH);
        u0 = rv ? a : 0u;
        u1 = rv ? b : 0u;
    };

    float sI0=0,sII0=0,sP0=0,sIp0=0;   // main gp col-sums (slot l)
    float sI1=0,sII1=0,sP1=0,sIp1=0;   // halo gp col-sums (slot 64+l, l<28)
    float sA0=0,sB0=0;                 // ab col-sums, main slot l (ab col c0-7+l)
    float sA1=0,sB1=0;                 // ab col-sums, halo slot 64+l (l<14)

    // warm-up: gp window(t0-1) for t0=y0-7 covers rows [y0-15, y0-1]
    for (int r = y0 - 15; r <= y0 - 1; ++r) {
        unsigned u0,u1; loadgp(r, u0,u1);
        float g0=bf_lo(u0), p0=bf_hi(u0), g1=bf_lo(u1), p1=bf_hi(u1);
        sI0+=g0; sII0+=g0*g0; sP0+=p0; sIp0+=g0*p0;
        sI1+=g1; sII1+=g1*g1; sP1+=p1; sIp1+=g1*p1;
    }
    unsigned adG0, adG1, sbG0, sbG1;
    loadgp(y0,      adG0, adG1);     // add row for t=y0-7: t+7 = y0
    loadgp(y0 - 15, sbG0, sbG1);     // sub row for t=y0-7: t-8 = y0-15

    // prefetched emit operands (smoky/rho at emit row, col c0+l)
    float es0,es1,es2, er0,er1,er2;
    auto loademit = [&](int e) {
        size_t off = (size_t)e*WW + c0 + l;
        es0 = sP[off]; es1 = sP[off+PLANE]; es2 = sP[off+2*PLANE];
        er0 = rP[off]; er1 = rP[off+PLANE]; er2 = rP[off+2*PLANE];
    };
    loademit(y0);

    float* E1 = &ex1[w][0];
    unsigned* RG = &ring[w][0][0];
    float2* E2 = &ex2[w][0];

    auto tsum = [&](const float* p) {
        return ((((p[0]+p[1])+(p[2]+p[3])) + ((p[4]+p[5])+(p[6]+p[7])))
              + (((p[8]+p[9])+(p[10]+p[11])) + ((p[12]+p[13])+p[14])));
    };

    const float inv225 = 1.0f/225.0f;
    const float inv11  = 1.0f/1.1f;
    const float third  = 1.0f/3.0f;

    for (int t = y0 - 7; t <= y0 + RSF + 6; ++t) {
        // 1. slide gp col-sums: +row(t+7) -row(t-8)
        {
            float gA0=bf_lo(adG0), pA0=bf_hi(adG0), gA1=bf_lo(adG1), pA1=bf_hi(adG1);
            float gS0=bf_lo(sbG0), pS0=bf_hi(sbG0), gS1=bf_lo(sbG1), pS1=bf_hi(sbG1);
            sI0 += gA0-gS0; sII0 += gA0*gA0-gS0*gS0; sP0 += pA0-pS0; sIp0 += gA0*pA0-gS0*pS0;
            sI1 += gA1-gS1; sII1 += gA1*gA1-gS1*gS1; sP1 += pA1-pS1; sIp1 += gA1*pA1-gS1*pS1;
        }
        // 2. capture emit operands before prefetch overwrites
        bool emitNow = (t >= y0 + 7);
        float cs0=es0, cs1=es1, cs2=es2, cr0=er0, cr1=er1, cr2=er2;
        // 3. prefetch next iteration's operands
        loadgp(t + 8, adG0, adG1);
        loadgp(t - 7, sbG0, sbG1);
        loademit(min(max(t - 6, y0), y0 + RSF - 1));
        // 4. exchange 1: gp col-sums -> a,b at row t
        E1[l]       = sI0;  E1[96+l]  = sII0;  E1[192+l]  = sP0;  E1[288+l]  = sIp0;
        if (l < 28) {
            E1[64+l] = sI1; E1[160+l] = sII1; E1[256+l] = sP1; E1[352+l] = sIp1;
        }
        LDS_WAIT();
        float SI0 = tsum(&E1[l]),    SII0 = tsum(&E1[96+l]);
        float SP0 = tsum(&E1[192+l]), SIp0 = tsum(&E1[288+l]);
        float SI1=0, SII1_=0, SP1_=0, SIp1_=0;
        if (l < 14) {
            SI1   = tsum(&E1[64+l]);  SII1_ = tsum(&E1[160+l]);
            SP1_  = tsum(&E1[256+l]); SIp1_ = tsum(&E1[352+l]);
        }
        WAVE_FENCE();   // keep next iter's E1 writes below these reads
        bool validT = ((unsigned)t < (unsigned)HH);
        unsigned pk0 = 0u, pk1 = 0u;
        {
            float mI = SI0*inv225, mP = SP0*inv225;
            float a = (SIp0*inv225 - mI*mP) / (SII0*inv225 - mI*mI + 1e-3f);
            unsigned pk = packbf(a, mP - a*mI);
            pk0 = validT ? pk : 0u;
        }
        if (l < 14) {
            float mI = SI1*inv225, mP = SP1_*inv225;
            float a = (SIp1_*inv225 - mI*mP) / (SII1_*inv225 - mI*mI + 1e-3f);
            unsigned pk = packbf(a, mP - a*mI);
            pk1 = validT ? pk : 0u;
        }
        // 5. ring: slide ab col-sums (+row t, -row t-15). bf16-rounded on both sides.
        unsigned old0 = RG[((t+1)&15)*80 + l];             // row t-15 slot
        unsigned old1 = (l < 14) ? RG[((t+1)&15)*80 + 64 + l] : 0u;
        RG[(t&15)*80 + l] = pk0;
        if (l < 14) RG[(t&15)*80 + 64 + l] = pk1;
        bool subOK = (t - 15 >= y0 - 7);
        float oa0 = subOK ? bf_lo(old0) : 0.f, ob0 = subOK ? bf_hi(old0) : 0.f;
        float oa1 = subOK ? bf_lo(old1) : 0.f, ob1 = subOK ? bf_hi(old1) : 0.f;
        sA0 += bf_lo(pk0) - oa0;  sB0 += bf_hi(pk0) - ob0;
        sA1 += bf_lo(pk1) - oa1;  sB1 += bf_hi(pk1) - ob1;
        WAVE_FENCE();
        // 6. exchange 2 + emit row e = t-7
        if (emitNow) {
            E2[l] = make_float2(sA0, sB0);
            if (l < 14) E2[64+l] = make_float2(sA1, sB1);
            LDS_WAIT();
            float SA, SB;
            {
                float2 u0=E2[l],   u1=E2[l+1],  u2=E2[l+2],  u3=E2[l+3],  u4=E2[l+4];
                float2 u5=E2[l+5], u6=E2[l+6],  u7=E2[l+7],  u8=E2[l+8],  u9=E2[l+9];
                float2 ua=E2[l+10],ub=E2[l+11], uc=E2[l+12], ud=E2[l+13], ue=E2[l+14];
                SA = ((((u0.x+u1.x)+(u2.x+u3.x)) + ((u4.x+u5.x)+(u6.x+u7.x)))
                   + (((u8.x+u9.x)+(ua.x+ub.x)) + ((uc.x+ud.x)+ue.x)));
                SB = ((((u0.y+u1.y)+(u2.y+u3.y)) + ((u4.y+u5.y)+(u6.y+u7.y)))
                   + (((u8.y+u9.y)+(ua.y+ub.y)) + ((uc.y+ud.y)+ue.y)));
            }
            WAVE_FENCE();
            float g = (cs0 + cs1 + cs2) * third;
            float f = (0.1f + SA*inv225*g + SB*inv225) * inv11;
            int e = t - 7;
            size_t off = (size_t)e*WW + c0 + l;
            oP[off]          = cs0 - f*(1.0f - cr0);
            oP[off+PLANE]    = cs1 - f*(1.0f - cr1);
            oP[off+2*PLANE]  = cs2 - f*(1.0f - cr2);
        }
    }
}

extern "C" void kernel_launch(void* const* d_in, const int* in_sizes, int n_in,
                              void* d_out, int out_size, void* d_ws, size_t ws_size,
                              hipStream_t stream) {
    const float* smoky = (const float*)d_in[0];
    const float* rho   = (const float*)d_in[1];
    float* out = (float*)d_out;
    unsigned* gpbuf = (unsigned*)d_ws;    // packed bf16 (guide,p): BATCH*PLANE u32

    k1_guide_minpool<<<BATCH*64, 256, 0, stream>>>(smoky, gpbuf);
    k23<<<BATCH*64, 256, 0, stream>>>(gpbuf, smoky, rho, out);
}

// Round 14
// 82.134 us; speedup vs baseline: 1.4863x; 1.4863x over previous
//
#include <hip/hip_runtime.h>

#define BATCH 16
#define HH 512
#define WW 512
#define PLANE (HH*WW)

// Compiler memory-order fences for wave-synchronous LDS exchange.
#define LDS_WAIT()   asm volatile("s_waitcnt lgkmcnt(0)" ::: "memory")
#define WAVE_FENCE() asm volatile("" ::: "memory")

// bf16 pair helpers: word = x in low 16 bits, y in high 16 bits
__device__ __forceinline__ float bf_lo(unsigned u) {
    union { unsigned u; float f; } c; c.u = u << 16; return c.f;
}
__device__ __forceinline__ float bf_hi(unsigned u) {
    union { unsigned u; float f; } c; c.u = u & 0xFFFF0000u; return c.f;
}
__device__ __forceinline__ unsigned f2bf(float f) {   // RTNE, returns low-16 bf16
    union { float f; unsigned u; } c; c.f = f;
    return (c.u + 0x7FFFu + ((c.u >> 16) & 1u)) >> 16;
}
__device__ __forceinline__ unsigned packbf(float x, float y) {
    return f2bf(x) | (f2bf(y) << 16);
}
__device__ __forceinline__ float min3f(float a, float b, float c) {
    return fminf(fminf(a, b), c);    // clang fuses to v_min3_f32
}

// balanced-tree 15-tap sum (depth 4)
__device__ __forceinline__ float tsum15(const float* p) {
    return ((((p[0]+p[1])+(p[2]+p[3])) + ((p[4]+p[5])+(p[6]+p[7])))
          + (((p[8]+p[9])+(p[10]+p[11])) + ((p[12]+p[13])+p[14])));
}

// ---------------- K1: guide (channel mean) + 15x15 replicate min-pool -> packed bf16 (g,p) ----------------
#define T1 64
#define HALO 7
#define LW (T1 + 2*HALO)   // 78

__global__ __launch_bounds__(256) void k1_guide_minpool(
    const float* __restrict__ smoky, unsigned* __restrict__ gp)
{
    __shared__ float dcp[LW*LW];          // per-pixel channel min, with replicate halo
    __shared__ float vmn[T1*LW];          // vertical 15-min
    __shared__ unsigned short gsh[T1*T1]; // guide (bf16) for interior
    int nwg = gridDim.x;             // 1024, divisible by 8
    int wg = (blockIdx.x & 7) * (nwg >> 3) + (blockIdx.x >> 3);  // XCD-chunked swizzle
    int img  = wg >> 6;              // 64 tiles per image
    int tile = wg & 63;
    int y0 = (tile >> 3) * T1;
    int x0 = (tile & 7) * T1;
    int t = threadIdx.x;
    const float* s0 = smoky + (size_t)img * 3 * PLANE;
    unsigned* gpl = gp + (size_t)img * PLANE;

    for (int i = t; i < LW*LW; i += 256) {
        int ly = i / LW, lx = i - ly * LW;
        int iy = y0 - HALO + ly, ix = x0 - HALO + lx;
        int cy = min(max(iy, 0), HH-1);
        int cx = min(max(ix, 0), WW-1);
        const float* bp = s0 + cy * WW + cx;
        float c0 = bp[0], c1 = bp[PLANE], c2 = bp[2*PLANE];
        dcp[i] = min3f(c0, c1, c2);
        if (ly >= HALO && ly < HALO+T1 && lx >= HALO && lx < HALO+T1)
            gsh[(ly-HALO)*T1 + (lx-HALO)] = (unsigned short)f2bf((c0 + c1 + c2) * (1.0f/3.0f));
    }
    __syncthreads();
    for (int i = t; i < T1*LW; i += 256) {
        int r = i / LW, c = i - r * LW;
        const float* q = &dcp[r*LW + c];
        float m = min3f(min3f(min3f(q[0*LW],q[1*LW],q[2*LW]),
                              min3f(q[3*LW],q[4*LW],q[5*LW]),
                              min3f(q[6*LW],q[7*LW],q[8*LW])),
                        min3f(q[9*LW],q[10*LW],q[11*LW]),
                        min3f(q[12*LW],q[13*LW],q[14*LW]));
        vmn[i] = m;
    }
    __syncthreads();
    for (int i = t; i < T1*T1; i += 256) {
        int r = i >> 6, c = i & 63;
        const float* q = &vmn[r*LW + c];
        float m = min3f(min3f(min3f(q[0],q[1],q[2]),
                              min3f(q[3],q[4],q[5]),
                              min3f(q[6],q[7],q[8])),
                        min3f(q[9],q[10],q[11]),
                        min3f(q[12],q[13],q[14]));
        gpl[(y0+r)*WW + x0 + c] = (unsigned)gsh[r*T1+c] | (f2bf(m) << 16);
    }
}

// ================= K2: pair-row sliding box sums (I,II,p,Ip) -> packed bf16 (a,b) =================
// 2 output rows per LDS exchange: half the serialization points, 2x loads in flight.
#define RS2 16

__global__ __launch_bounds__(256) void k2_ab(
    const unsigned* __restrict__ gp, unsigned* __restrict__ abO)
{
    __shared__ float ls[4][2][4][80];   // [wave][row e/o][quantity][slot]
    int nwg = gridDim.x;             // 1024
    int wg = (blockIdx.x & 7) * (nwg >> 3) + (blockIdx.x >> 3);
    int w = threadIdx.x >> 6, l = threadIdx.x & 63;
    int gw = wg * 4 + w;             // 0..4095
    int img   = gw >> 8;             // 256 waves per image
    int cg    = (gw >> 5) & 7;
    int strip = gw & 31;
    int y0 = strip * RS2;
    int c0 = cg * 64;
    const unsigned* gpP = gp + (size_t)img * PLANE;
    unsigned* abP = abO + (size_t)img * PLANE;

    int col0 = c0 - 7 + l;      // slot l
    int col1 = c0 + 57 + l;     // slot 64+l (lanes 0..13)
    bool v0 = (col0 >= 0);
    bool v1 = (l < 14) && (col1 < WW);

    float sI0=0,sII0=0,sP0=0,sIp0=0;
    float sI1=0,sII1=0,sP1=0,sIp1=0;

    auto loadrow = [&](int y, unsigned& u0, unsigned& u1) {
        int yc = min(max(y, 0), HH-1);
        const unsigned* r = gpP + (size_t)yc * WW;
        unsigned a = 0u, b = 0u;
        if (v0) a = r[col0];
        if (v1) b = r[col1];
        bool rv = ((unsigned)y < (unsigned)HH);
        u0 = rv ? a : 0u;
        u1 = rv ? b : 0u;
    };

    // warm-up: window(y0-1) = rows y0-8 .. y0+6
    for (int r = y0 - 8; r <= y0 + 6; ++r) {
        unsigned u0,u1; loadrow(r, u0,u1);
        float g0=bf_lo(u0), p0=bf_hi(u0), g1=bf_lo(u1), p1=bf_hi(u1);
        sI0+=g0; sII0+=g0*g0; sP0+=p0; sIp0+=g0*p0;
        sI1+=g1; sII1+=g1*g1; sP1+=p1; sIp1+=g1*p1;
    }
    unsigned a1M,a1H, s1M,s1H, a2M,a2H, s2M,s2H;
    loadrow(y0 + 7, a1M, a1H);   // add for even row
    loadrow(y0 - 8, s1M, s1H);   // sub for even row
    loadrow(y0 + 8, a2M, a2H);   // add for odd row
    loadrow(y0 - 7, s2M, s2H);   // sub for odd row

    float* Le = &ls[w][0][0][0];
    float* Lo = &ls[w][1][0][0];
    const float inv225 = 1.0f/225.0f;

    for (int y = y0; y < y0 + RS2; y += 2) {
        // even window y
        {
            float gA=bf_lo(a1M), pA=bf_hi(a1M), gS=bf_lo(s1M), pS=bf_hi(s1M);
            sI0 += gA-gS; sII0 += gA*gA-gS*gS; sP0 += pA-pS; sIp0 += gA*pA-gS*pS;
            float gAh=bf_lo(a1H), pAh=bf_hi(a1H), gSh=bf_lo(s1H), pSh=bf_hi(s1H);
            sI1 += gAh-gSh; sII1 += gAh*gAh-gSh*gSh; sP1 += pAh-pSh; sIp1 += gAh*pAh-gSh*pSh;
        }
        float eI0=sI0, eII0=sII0, eP0=sP0, eIp0=sIp0;
        float eI1=sI1, eII1=sII1, eP1=sP1, eIp1=sIp1;
        // odd window y+1
        {
            float gA=bf_lo(a2M), pA=bf_hi(a2M), gS=bf_lo(s2M), pS=bf_hi(s2M);
            sI0 += gA-gS; sII0 += gA*gA-gS*gS; sP0 += pA-pS; sIp0 += gA*pA-gS*pS;
            float gAh=bf_lo(a2H), pAh=bf_hi(a2H), gSh=bf_lo(s2H), pSh=bf_hi(s2H);
            sI1 += gAh-gSh; sII1 += gAh*gAh-gSh*gSh; sP1 += pAh-pSh; sIp1 += gAh*pAh-gSh*pSh;
        }
        // prefetch next iteration's 4 row-pairs
        loadrow(y + 9,  a1M, a1H);
        loadrow(y - 6,  s1M, s1H);
        loadrow(y + 10, a2M, a2H);
        loadrow(y - 5,  s2M, s2H);
        // single exchange for both rows
        Le[l] = eI0; Le[80+l] = eII0; Le[160+l] = eP0; Le[240+l] = eIp0;
        Lo[l] = sI0; Lo[80+l] = sII0; Lo[160+l] = sP0; Lo[240+l] = sIp0;
        if (l < 14) {
            Le[64+l] = eI1; Le[144+l] = eII1; Le[224+l] = eP1; Le[304+l] = eIp1;
            Lo[64+l] = sI1; Lo[144+l] = sII1; Lo[224+l] = sP1; Lo[304+l] = sIp1;
        }
        LDS_WAIT();
        float SIe  = tsum15(&Le[l]),     SIIe = tsum15(&Le[80+l]);
        float SPe  = tsum15(&Le[160+l]), SIpe = tsum15(&Le[240+l]);
        float SIo  = tsum15(&Lo[l]),     SIIo = tsum15(&Lo[80+l]);
        float SPo  = tsum15(&Lo[160+l]), SIpo = tsum15(&Lo[240+l]);
        WAVE_FENCE();   // keep next iter's ds_writes below these reads
        {
            float mI = SIe*inv225, mP = SPe*inv225;
            float va = (SIpe*inv225 - mI*mP) / (SIIe*inv225 - mI*mI + 1e-3f);
            abP[(size_t)y*WW + c0 + l] = packbf(va, mP - va*mI);
        }
        {
            float mI = SIo*inv225, mP = SPo*inv225;
            float va = (SIpo*inv225 - mI*mP) / (SIIo*inv225 - mI*mI + 1e-3f);
            abP[(size_t)(y+1)*WW + c0 + l] = packbf(va, mP - va*mI);
        }
    }
}

// ================= K3: pair-row sliding box sums of (a,b) + guided output + combine =================
__global__ __launch_bounds__(256) void k3_final(
    const unsigned* __restrict__ abI,
    const float* __restrict__ smoky, const float* __restrict__ rho,
    float* __restrict__ out)
{
    __shared__ float ls[4][2][2][80];   // [wave][row e/o][quantity][slot]
    int nwg = gridDim.x;             // 1024
    int wg = (blockIdx.x & 7) * (nwg >> 3) + (blockIdx.x >> 3);
    int w = threadIdx.x >> 6, l = threadIdx.x & 63;
    int gw = wg * 4 + w;
    int img   = gw >> 8;
    int cg    = (gw >> 5) & 7;
    int strip = gw & 31;
    int y0 = strip * RS2;
    int c0 = cg * 64;
    const unsigned* abP = abI + (size_t)img * PLANE;
    const float* sP = smoky + (size_t)img * 3 * PLANE;
    const float* rP = rho   + (size_t)img * 3 * PLANE;
    float* oP = out + (size_t)img * 3 * PLANE;

    int col0 = c0 - 7 + l;
    int col1 = c0 + 57 + l;
    bool v0 = (col0 >= 0);
    bool v1 = (l < 14) && (col1 < WW);

    float sa0=0, sb0=0, sa1=0, sb1=0;

    auto loadrow = [&](int y, unsigned& u0, unsigned& u1) {
        int yc = min(max(y, 0), HH-1);
        const unsigned* r = abP + (size_t)yc * WW;
        unsigned a = 0u, b = 0u;
        if (v0) a = r[col0];
        if (v1) b = r[col1];
        bool rv = ((unsigned)y < (unsigned)HH);
        u0 = rv ? a : 0u;
        u1 = rv ? b : 0u;
    };

    for (int r = y0 - 8; r <= y0 + 6; ++r) {
        unsigned u0,u1; loadrow(r, u0,u1);
        sa0 += bf_lo(u0); sb0 += bf_hi(u0);
        sa1 += bf_lo(u1); sb1 += bf_hi(u1);
    }
    unsigned a1M,a1H, s1M,s1H, a2M,a2H, s2M,s2H;
    loadrow(y0 + 7, a1M, a1H);
    loadrow(y0 - 8, s1M, s1H);
    loadrow(y0 + 8, a2M, a2H);
    loadrow(y0 - 7, s2M, s2H);

    // prefetched emit operands for the row pair (smoky/rho), branchless clamp
    float esA0,esA1,esA2, erA0,erA1,erA2;   // even row
    float esB0,esB1,esB2, erB0,erB1,erB2;   // odd row
    int yend = y0 + RS2;
    auto loademit = [&](int y,
                        float& e0, float& e1, float& e2,
                        float& r0, float& r1, float& r2) {
        int e = min(y, yend - 1);
        size_t off = (size_t)e*WW + c0 + l;
        e0 = sP[off]; e1 = sP[off+PLANE]; e2 = sP[off+2*PLANE];
        r0 = rP[off]; r1 = rP[off+PLANE]; r2 = rP[off+2*PLANE];
    };
    loademit(y0,     esA0,esA1,esA2, erA0,erA1,erA2);
    loademit(y0 + 1, esB0,esB1,esB2, erB0,erB1,erB2);

    float* Le = &ls[w][0][0][0];
    float* Lo = &ls[w][1][0][0];
    const float inv225 = 1.0f/225.0f;
    const float inv11  = 1.0f/1.1f;
    const float third  = 1.0f/3.0f;
    for (int y = y0; y < yend; y += 2) {
        // even window y
        sa0 += bf_lo(a1M) - bf_lo(s1M);  sb0 += bf_hi(a1M) - bf_hi(s1M);
        sa1 += bf_lo(a1H) - bf_lo(s1H);  sb1 += bf_hi(a1H) - bf_hi(s1H);
        float ea0=sa0, eb0=sb0, ea1=sa1, eb1=sb1;
        // odd window y+1
        sa0 += bf_lo(a2M) - bf_lo(s2M);  sb0 += bf_hi(a2M) - bf_hi(s2M);
        sa1 += bf_lo(a2H) - bf_lo(s2H);  sb1 += bf_hi(a2H) - bf_hi(s2H);
        // capture emit operands
        float cA0=esA0, cA1=esA1, cA2=esA2, dA0=erA0, dA1=erA1, dA2=erA2;
        float cB0=esB0, cB1=esB1, cB2=esB2, dB0=erB0, dB1=erB1, dB2=erB2;
        // prefetch next iteration
        loadrow(y + 9,  a1M, a1H);
        loadrow(y - 6,  s1M, s1H);
        loadrow(y + 10, a2M, a2H);
        loadrow(y - 5,  s2M, s2H);
        loademit(y + 2, esA0,esA1,esA2, erA0,erA1,erA2);
        loademit(y + 3, esB0,esB1,esB2, erB0,erB1,erB2);
        // single exchange for both rows
        Le[l] = ea0; Le[80+l] = eb0;
        Lo[l] = sa0; Lo[80+l] = sb0;
        if (l < 14) {
            Le[64+l] = ea1; Le[144+l] = eb1;
            Lo[64+l] = sa1; Lo[144+l] = sb1;
        }
        LDS_WAIT();
        float SAe = tsum15(&Le[l]), SBe = tsum15(&Le[80+l]);
        float SAo = tsum15(&Lo[l]), SBo = tsum15(&Lo[80+l]);
        WAVE_FENCE();
        // emit even row
        {
            float g = (cA0 + cA1 + cA2) * third;
            float f = (0.1f + SAe*inv225*g + SBe*inv225) * inv11;
            size_t off = (size_t)y*WW + c0 + l;
            oP[off]          = cA0 - f*(1.0f - dA0);
            oP[off+PLANE]    = cA1 - f*(1.0f - dA1);
            oP[off+2*PLANE]  = cA2 - f*(1.0f - dA2);
        }
        // emit odd row
        {
            float g = (cB0 + cB1 + cB2) * third;
            float f = (0.1f + SAo*inv225*g + SBo*inv225) * inv11;
            size_t off = (size_t)(y+1)*WW + c0 + l;
            oP[off]          = cB0 - f*(1.0f - dB0);
            oP[off+PLANE]    = cB1 - f*(1.0f - dB1);
            oP[off+2*PLANE]  = cB2 - f*(1.0f - dB2);
        }
    }
}

extern "C" void kernel_launch(void* const* d_in, const int* in_sizes, int n_in,
                              void* d_out, int out_size, void* d_ws, size_t ws_size,
                              hipStream_t stream) {
    const float* smoky = (const float*)d_in[0];
    const float* rho   = (const float*)d_in[1];
    float* out = (float*)d_out;
    const size_t P = (size_t)BATCH * PLANE;
    unsigned* gpbuf = (unsigned*)d_ws;        // packed bf16 (guide,p): P u32
    unsigned* abbuf = (unsigned*)d_ws + P;    // packed bf16 (a,b): P u32

    k1_guide_minpool<<<BATCH*64, 256, 0, stream>>>(smoky, gpbuf);
    k2_ab<<<BATCH*64, 256, 0, stream>>>(gpbuf, abbuf);
    k3_final<<<BATCH*64, 256, 0, stream>>>(abbuf, smoky, rho, out);
}

// Round 15
// 76.251 us; speedup vs baseline: 1.6010x; 1.0771x over previous
//
#include <hip/hip_runtime.h>

#define BATCH 16
#define HH 512
#define WW 512
#define PLANE (HH*WW)

// Compiler memory-order fences for wave-synchronous LDS exchange.
#define LDS_WAIT()   asm volatile("s_waitcnt lgkmcnt(0)" ::: "memory")
#define WAVE_FENCE() asm volatile("" ::: "memory")

// bf16 pair helpers: word = x in low 16 bits, y in high 16 bits
__device__ __forceinline__ float bf_lo(unsigned u) {
    union { unsigned u; float f; } c; c.u = u << 16; return c.f;
}
__device__ __forceinline__ float bf_hi(unsigned u) {
    union { unsigned u; float f; } c; c.u = u & 0xFFFF0000u; return c.f;
}
__device__ __forceinline__ unsigned f2bf(float f) {   // RTNE, returns low-16 bf16
    union { float f; unsigned u; } c; c.f = f;
    return (c.u + 0x7FFFu + ((c.u >> 16) & 1u)) >> 16;
}
__device__ __forceinline__ unsigned packbf(float x, float y) {
    return f2bf(x) | (f2bf(y) << 16);
}
__device__ __forceinline__ float min3f(float a, float b, float c) {
    return fminf(fminf(a, b), c);    // clang fuses to v_min3_f32
}
__device__ __forceinline__ float4 add4(float4 a, float4 b) {
    return make_float4(a.x+b.x, a.y+b.y, a.z+b.z, a.w+b.w);
}
// balanced-tree 15-tap sum over float4 slots: 15 x ds_read_b128 (one LDS instr
// returns all 4 packed quantities) instead of 60 x ds_read_b32.
__device__ __forceinline__ float4 tsum15v(const float4* p) {
    float4 s = add4(add4(add4(p[0],p[1]),add4(p[2],p[3])),
                    add4(add4(p[4],p[5]),add4(p[6],p[7])));
    float4 u = add4(add4(add4(p[8],p[9]),add4(p[10],p[11])),
                    add4(add4(p[12],p[13]),p[14]));
    return add4(s, u);
}

// ---------------- K1: guide (channel mean) + 15x15 replicate min-pool -> packed bf16 (g,p) ----------------
#define T1 64
#define HALO 7
#define LW (T1 + 2*HALO)   // 78

__global__ __launch_bounds__(256) void k1_guide_minpool(
    const float* __restrict__ smoky, unsigned* __restrict__ gp)
{
    __shared__ float dcp[LW*LW];          // per-pixel channel min, with replicate halo
    __shared__ float vmn[T1*LW];          // vertical 15-min
    __shared__ unsigned short gsh[T1*T1]; // guide (bf16) for interior
    int nwg = gridDim.x;             // 1024, divisible by 8
    int wg = (blockIdx.x & 7) * (nwg >> 3) + (blockIdx.x >> 3);  // XCD-chunked swizzle
    int img  = wg >> 6;              // 64 tiles per image
    int tile = wg & 63;
    int y0 = (tile >> 3) * T1;
    int x0 = (tile & 7) * T1;
    int t = threadIdx.x;
    const float* s0 = smoky + (size_t)img * 3 * PLANE;
    unsigned* gpl = gp + (size_t)img * PLANE;

    for (int i = t; i < LW*LW; i += 256) {
        int ly = i / LW, lx = i - ly * LW;
        int iy = y0 - HALO + ly, ix = x0 - HALO + lx;
        int cy = min(max(iy, 0), HH-1);
        int cx = min(max(ix, 0), WW-1);
        const float* bp = s0 + cy * WW + cx;
        float c0 = bp[0], c1 = bp[PLANE], c2 = bp[2*PLANE];
        dcp[i] = min3f(c0, c1, c2);
        if (ly >= HALO && ly < HALO+T1 && lx >= HALO && lx < HALO+T1)
            gsh[(ly-HALO)*T1 + (lx-HALO)] = (unsigned short)f2bf((c0 + c1 + c2) * (1.0f/3.0f));
    }
    __syncthreads();
    for (int i = t; i < T1*LW; i += 256) {
        int r = i / LW, c = i - r * LW;
        const float* q = &dcp[r*LW + c];
        float m = min3f(min3f(min3f(q[0*LW],q[1*LW],q[2*LW]),
                              min3f(q[3*LW],q[4*LW],q[5*LW]),
                              min3f(q[6*LW],q[7*LW],q[8*LW])),
                        min3f(q[9*LW],q[10*LW],q[11*LW]),
                        min3f(q[12*LW],q[13*LW],q[14*LW]));
        vmn[i] = m;
    }
    __syncthreads();
    for (int i = t; i < T1*T1; i += 256) {
        int r = i >> 6, c = i & 63;
        const float* q = &vmn[r*LW + c];
        float m = min3f(min3f(min3f(q[0],q[1],q[2]),
                              min3f(q[3],q[4],q[5]),
                              min3f(q[6],q[7],q[8])),
                        min3f(q[9],q[10],q[11]),
                        min3f(q[12],q[13],q[14]));
        gpl[(y0+r)*WW + x0 + c] = (unsigned)gsh[r*T1+c] | (f2bf(m) << 16);
    }
}

// ================= K2: pair-row sliding box sums, quantity-packed float4 exchange =================
#define RS2 16

__global__ __launch_bounds__(256) void k2_ab(
    const unsigned* __restrict__ gp, unsigned* __restrict__ abO)
{
    __shared__ float4 ls[4][2][80];   // [wave][row e/o][slot] slot=(sI,sII,sP,sIp)
    int nwg = gridDim.x;             // 1024
    int wg = (blockIdx.x & 7) * (nwg >> 3) + (blockIdx.x >> 3);
    int w = threadIdx.x >> 6, l = threadIdx.x & 63;
    int gw = wg * 4 + w;             // 0..4095
    int img   = gw >> 8;             // 256 waves per image
    int cg    = (gw >> 5) & 7;
    int strip = gw & 31;
    int y0 = strip * RS2;
    int c0 = cg * 64;
    const unsigned* gpP = gp + (size_t)img * PLANE;
    unsigned* abP = abO + (size_t)img * PLANE;

    int col0 = c0 - 7 + l;      // slot l
    int col1 = c0 + 57 + l;     // slot 64+l (lanes 0..13)
    bool v0 = (col0 >= 0);
    bool v1 = (l < 14) && (col1 < WW);

    float sI0=0,sII0=0,sP0=0,sIp0=0;
    float sI1=0,sII1=0,sP1=0,sIp1=0;

    auto loadrow = [&](int y, unsigned& u0, unsigned& u1) {
        int yc = min(max(y, 0), HH-1);
        const unsigned* r = gpP + (size_t)yc * WW;
        unsigned a = 0u, b = 0u;
        if (v0) a = r[col0];
        if (v1) b = r[col1];
        bool rv = ((unsigned)y < (unsigned)HH);
        u0 = rv ? a : 0u;
        u1 = rv ? b : 0u;
    };

    // warm-up: window(y0-1) = rows y0-8 .. y0+6
    for (int r = y0 - 8; r <= y0 + 6; ++r) {
        unsigned u0,u1; loadrow(r, u0,u1);
        float g0=bf_lo(u0), p0=bf_hi(u0), g1=bf_lo(u1), p1=bf_hi(u1);
        sI0+=g0; sII0+=g0*g0; sP0+=p0; sIp0+=g0*p0;
        sI1+=g1; sII1+=g1*g1; sP1+=p1; sIp1+=g1*p1;
    }
    unsigned a1M,a1H, s1M,s1H, a2M,a2H, s2M,s2H;
    loadrow(y0 + 7, a1M, a1H);   // add for even row
    loadrow(y0 - 8, s1M, s1H);   // sub for even row
    loadrow(y0 + 8, a2M, a2H);   // add for odd row
    loadrow(y0 - 7, s2M, s2H);   // sub for odd row

    float4* Le = &ls[w][0][0];
    float4* Lo = &ls[w][1][0];
    const float inv225 = 1.0f/225.0f;

    for (int y = y0; y < y0 + RS2; y += 2) {
        // even window y
        {
            float gA=bf_lo(a1M), pA=bf_hi(a1M), gS=bf_lo(s1M), pS=bf_hi(s1M);
            sI0 += gA-gS; sII0 += gA*gA-gS*gS; sP0 += pA-pS; sIp0 += gA*pA-gS*pS;
            float gAh=bf_lo(a1H), pAh=bf_hi(a1H), gSh=bf_lo(s1H), pSh=bf_hi(s1H);
            sI1 += gAh-gSh; sII1 += gAh*gAh-gSh*gSh; sP1 += pAh-pSh; sIp1 += gAh*pAh-gSh*pSh;
        }
        float eI0=sI0, eII0=sII0, eP0=sP0, eIp0=sIp0;
        float eI1=sI1, eII1=sII1, eP1=sP1, eIp1=sIp1;
        // odd window y+1
        {
            float gA=bf_lo(a2M), pA=bf_hi(a2M), gS=bf_lo(s2M), pS=bf_hi(s2M);
            sI0 += gA-gS; sII0 += gA*gA-gS*gS; sP0 += pA-pS; sIp0 += gA*pA-gS*pS;
            float gAh=bf_lo(a2H), pAh=bf_hi(a2H), gSh=bf_lo(s2H), pSh=bf_hi(s2H);
            sI1 += gAh-gSh; sII1 += gAh*gAh-gSh*gSh; sP1 += pAh-pSh; sIp1 += gAh*pAh-gSh*pSh;
        }
        // prefetch next iteration's 4 row-pairs
        loadrow(y + 9,  a1M, a1H);
        loadrow(y - 6,  s1M, s1H);
        loadrow(y + 10, a2M, a2H);
        loadrow(y - 5,  s2M, s2H);
        // single packed exchange for both rows (ds_write_b128)
        Le[l] = make_float4(eI0, eII0, eP0, eIp0);
        Lo[l] = make_float4(sI0, sII0, sP0, sIp0);
        if (l < 14) {
            Le[64+l] = make_float4(eI1, eII1, eP1, eIp1);
            Lo[64+l] = make_float4(sI1, sII1, sP1, sIp1);
        }
        LDS_WAIT();
        float4 Te = tsum15v(&Le[l]);   // 15 x b128: all 4 quantities per read
        float4 To = tsum15v(&Lo[l]);
        WAVE_FENCE();   // keep next iter's ds_writes below these reads
        {
            float mI = Te.x*inv225, mP = Te.z*inv225;
            float va = (Te.w*inv225 - mI*mP) / (Te.y*inv225 - mI*mI + 1e-3f);
            abP[(size_t)y*WW + c0 + l] = packbf(va, mP - va*mI);
        }
        {
            float mI = To.x*inv225, mP = To.z*inv225;
            float va = (To.w*inv225 - mI*mP) / (To.y*inv225 - mI*mI + 1e-3f);
            abP[(size_t)(y+1)*WW + c0 + l] = packbf(va, mP - va*mI);
        }
    }
}

// ================= K3: pair-row sliding box sums of (a,b), float4-packed exchange =================
// slot = (a_even, b_even, a_odd, b_odd): one 15-tap b128 pass serves both rows.
__global__ __launch_bounds__(256) void k3_final(
    const unsigned* __restrict__ abI,
    const float* __restrict__ smoky, const float* __restrict__ rho,
    float* __restrict__ out)
{
    __shared__ float4 ls[4][80];     // [wave][slot]
    int nwg = gridDim.x;             // 1024
    int wg = (blockIdx.x & 7) * (nwg >> 3) + (blockIdx.x >> 3);
    int w = threadIdx.x >> 6, l = threadIdx.x & 63;
    int gw = wg * 4 + w;
    int img   = gw >> 8;
    int cg    = (gw >> 5) & 7;
    int strip = gw & 31;
    int y0 = strip * RS2;
    int c0 = cg * 64;
    const unsigned* abP = abI + (size_t)img * PLANE;
    const float* sP = smoky + (size_t)img * 3 * PLANE;
    const float* rP = rho   + (size_t)img * 3 * PLANE;
    float* oP = out + (size_t)img * 3 * PLANE;

    int col0 = c0 - 7 + l;
    int col1 = c0 + 57 + l;
    bool v0 = (col0 >= 0);
    bool v1 = (l < 14) && (col1 < WW);

    float sa0=0, sb0=0, sa1=0, sb1=0;

    auto loadrow = [&](int y, unsigned& u0, unsigned& u1) {
        int yc = min(max(y, 0), HH-1);
        const unsigned* r = abP + (size_t)yc * WW;
        unsigned a = 0u, b = 0u;
        if (v0) a = r[col0];
        if (v1) b = r[col1];
        bool rv = ((unsigned)y < (unsigned)HH);
        u0 = rv ? a : 0u;
        u1 = rv ? b : 0u;
    };

    for (int r = y0 - 8; r <= y0 + 6; ++r) {
        unsigned u0,u1; loadrow(r, u0,u1);
        sa0 += bf_lo(u0); sb0 += bf_hi(u0);
        sa1 += bf_lo(u1); sb1 += bf_hi(u1);
    }
    unsigned a1M,a1H, s1M,s1H, a2M,a2H, s2M,s2H;
    loadrow(y0 + 7, a1M, a1H);
    loadrow(y0 - 8, s1M, s1H);
    loadrow(y0 + 8, a2M, a2H);
    loadrow(y0 - 7, s2M, s2H);

    // prefetched emit operands for the row pair (smoky/rho), branchless clamp
    float esA0,esA1,esA2, erA0,erA1,erA2;   // even row
    float esB0,esB1,esB2, erB0,erB1,erB2;   // odd row
    int yend = y0 + RS2;
    auto loademit = [&](int y,
                        float& e0, float& e1, float& e2,
                        float& r0, float& r1, float& r2) {
        int e = min(y, yend - 1);
        size_t off = (size_t)e*WW + c0 + l;
        e0 = sP[off]; e1 = sP[off+PLANE]; e2 = sP[off+2*PLANE];
        r0 = rP[off]; r1 = rP[off+PLANE]; r2 = rP[off+2*PLANE];
    };
    loademit(y0,     esA0,esA1,esA2, erA0,erA1,erA2);
    loademit(y0 + 1, esB0,esB1,esB2, erB0,erB1,erB2);

    float4* L4 = &ls[w][0];
    const float inv225 = 1.0f/225.0f;
    const float inv11  = 1.0f/1.1f;
    const float third  = 1.0f/3.0f;
    for (int y = y0; y < yend; y += 2) {
        // even window y
        sa0 += bf_lo(a1M) - bf_lo(s1M);  sb0 += bf_hi(a1M) - bf_hi(s1M);
        sa1 += bf_lo(a1H) - bf_lo(s1H);  sb1 += bf_hi(a1H) - bf_hi(s1H);
        float ea0=sa0, eb0=sb0, ea1=sa1, eb1=sb1;
        // odd window y+1
        sa0 += bf_lo(a2M) - bf_lo(s2M);  sb0 += bf_hi(a2M) - bf_hi(s2M);
        sa1 += bf_lo(a2H) - bf_lo(s2H);  sb1 += bf_hi(a2H) - bf_hi(s2H);
        // capture emit operands
        float cA0=esA0, cA1=esA1, cA2=esA2, dA0=erA0, dA1=erA1, dA2=erA2;
        float cB0=esB0, cB1=esB1, cB2=esB2, dB0=erB0, dB1=erB1, dB2=erB2;
        // prefetch next iteration
        loadrow(y + 9,  a1M, a1H);
        loadrow(y - 6,  s1M, s1H);
        loadrow(y + 10, a2M, a2H);
        loadrow(y - 5,  s2M, s2H);
        loademit(y + 2, esA0,esA1,esA2, erA0,erA1,erA2);
        loademit(y + 3, esB0,esB1,esB2, erB0,erB1,erB2);
        // single packed exchange: slot = (a_e, b_e, a_o, b_o)
        L4[l] = make_float4(ea0, eb0, sa0, sb0);
        if (l < 14) L4[64+l] = make_float4(ea1, eb1, sa1, sb1);
        LDS_WAIT();
        float4 T = tsum15v(&L4[l]);   // both rows, both quantities in one pass
        WAVE_FENCE();
        // emit even row
        {
            float g = (cA0 + cA1 + cA2) * third;
            float f = (0.1f + T.x*inv225*g + T.y*inv225) * inv11;
            size_t off = (size_t)y*WW + c0 + l;
            oP[off]          = cA0 - f*(1.0f - dA0);
            oP[off+PLANE]    = cA1 - f*(1.0f - dA1);
            oP[off+2*PLANE]  = cA2 - f*(1.0f - dA2);
        }
        // emit odd row
        {
            float g = (cB0 + cB1 + cB2) * third;
            float f = (0.1f + T.z*inv225*g + T.w*inv225) * inv11;
            size_t off = (size_t)(y+1)*WW + c0 + l;
            oP[off]          = cB0 - f*(1.0f - dB0);
            oP[off+PLANE]    = cB1 - f*(1.0f - dB1);
            oP[off+2*PLANE]  = cB2 - f*(1.0f - dB2);
        }
    }
}

extern "C" void kernel_launch(void* const* d_in, const int* in_sizes, int n_in,
                              void* d_out, int out_size, void* d_ws, size_t ws_size,
                              hipStream_t stream) {
    const float* smoky = (const float*)d_in[0];
    const float* rho   = (const float*)d_in[1];
    float* out = (float*)d_out;
    const size_t P = (size_t)BATCH * PLANE;
    unsigned* gpbuf = (unsigned*)d_ws;        // packed bf16 (guide,p): P u32
    unsigned* abbuf = (unsigned*)d_ws + P;    // packed bf16 (a,b): P u32

    k1_guide_minpool<<<BATCH*64, 256, 0, stream>>>(smoky, gpbuf);
    k2_ab<<<BATCH*64, 256, 0, stream>>>(gpbuf, abbuf);
    k3_final<<<BATCH*64, 256, 0, stream>>>(abbuf, smoky, rho, out);
}